// Round 1
// baseline (832.823 us; speedup 1.0000x reference)
//
#include <hip/hip_runtime.h>

#define F 128
#define NNODE 2000
#define NEDGE 64000
#define NBATCH 4
#define NN 8000          // NBATCH*NNODE
#define NRELC 18
#define KTOP 800         // int(0.1*8000)
#define AVGLOG 3.4965075614664802f   // float(np.log(33.0))
#define EPSSTD 1e-5f

// ---------------- setup kernels ----------------

__global__ void k_init(float* __restrict__ cur, int* __restrict__ deg){
  int i = blockIdx.x*blockDim.x + threadIdx.x;
  int stride = gridDim.x*blockDim.x;
  for(int t=i;t<NN*F;t+=stride) cur[t]=0.f;
  for(int t=i;t<NNODE;t+=stride) deg[t]=0;
}

// single block: indices, rel_emb, Rb = rel@Wl[128:], initial scores, sel0, xr scatter
__global__ void k_meta(const int* __restrict__ h_index, const int* __restrict__ r_index,
                       const int* __restrict__ t_index, const float* __restrict__ hidden,
                       const float* __restrict__ rel_hidden, const float* __restrict__ rel_table,
                       const float* __restrict__ Wl, const float* __restrict__ bl,
                       const float* __restrict__ W1, const float* __restrict__ b1,
                       const float* __restrict__ W2, const float* __restrict__ b2,
                       float* __restrict__ cur, unsigned char* __restrict__ sel,
                       int* __restrict__ meta_i, float* __restrict__ meta_f){
  __shared__ int sh_ist[NBATCH], sh_h0[NBATCH], sh_t0[NBATCH], sh_r0[NBATCH];
  __shared__ float sh_rel[NBATCH*F];
  __shared__ float sh_z[F], sh_zz[F];
  __shared__ float sh_sc[NBATCH];
  __shared__ int sh_excl;
  int tid = threadIdx.x;
  if(tid<NBATCH){
    int b=tid;
    int h00=h_index[b*32];
    int ist=1;
    for(int j=1;j<32;j++) if(h_index[b*32+j]!=h00) ist=0;
    sh_ist[b]=ist;
    // is_t false: h_idx=t_index, t_idx=h_index, r+=NREL
    sh_h0[b] = (ist ? h_index[b*32] : t_index[b*32]) + b*NNODE;
    sh_t0[b] = (ist ? t_index[b*32] : h_index[b*32]) + b*NNODE;
    sh_r0[b] = r_index[b*32] + (ist?0:NRELC);
  }
  __syncthreads();
  if(tid<NBATCH*32){
    int b=tid>>5;
    meta_i[16+tid] = (sh_ist[b] ? t_index[tid] : h_index[tid]) + b*NNODE; // final gather idx
  }
  for(int t=tid;t<NBATCH*F;t+=blockDim.x){
    int b=t>>7, f=t&127;
    float v = rel_table[sh_r0[b]*F+f];
    sh_rel[t]=v; meta_f[t]=v;
  }
  __syncthreads();
  // Rb[b][f] = sum_k rel[b][k]*Wl[128+k][f]
  for(int t=tid;t<NBATCH*F;t+=blockDim.x){
    int b=t>>7, f=t&127;
    float acc=0.f;
    for(int k=0;k<F;k++) acc += sh_rel[b*F+k]*Wl[(F+k)*F+f];
    meta_f[512+t]=acc;
  }
  __syncthreads();
  // initial scores sc[b] = _score(hidden_b, rel_b)
  for(int b=0;b<NBATCH;b++){
    if(tid<F){
      float acc=0.f;
      for(int k=0;k<F;k++) acc += hidden[b*F+k]*Wl[k*F+tid];
      float heur = acc + meta_f[512+b*F+tid] + bl[tid];
      sh_z[tid] = heur*hidden[b*F+tid];
    }
    __syncthreads();
    if(tid<F){
      float acc=0.f;
      for(int k=0;k<F;k++) acc += sh_z[k]*W1[k*F+tid];
      acc += b1[tid];
      sh_zz[tid] = acc>0.f?acc:0.f;
    }
    __syncthreads();
    if(tid==0){
      float s=0.f;
      for(int k=0;k<F;k++) s += sh_zz[k]*W2[k];
      sh_sc[b] = s + b2[0];
      meta_f[1024+b]=sh_sc[b];
    }
    __syncthreads();
  }
  if(tid==0){
    // layer-0 top_k over repeat(s0,N): only first-8000 entries matter; all zero-ties
    // get selected (k-Z >= 1.59M >> 8000). Exclusion only if batch0's h0 node < 4
    // (so its repeated segment lands below 8000) AND its score is negative.
    sh_excl = (sh_h0[0]<4 && sh_sc[0]<0.f) ? sh_h0[0] : -1;
    meta_i[8]=sh_excl;
  }
  __syncthreads();
  int ex = sh_excl;
  for(int t=tid;t<NN;t+=blockDim.x)
    sel[t] = (ex>=0 && (t/NNODE)==ex) ? 0 : 1;
  // xr scatter: t rows first, then h rows (h wins collisions, matching .at[].set order)
  for(int t=tid;t<NBATCH*F;t+=blockDim.x){
    int b=t>>7, f=t&127;
    cur[sh_t0[b]*F+f] = rel_hidden[t];
  }
  __syncthreads();
  for(int t=tid;t<NBATCH*F;t+=blockDim.x){
    int b=t>>7, f=t&127;
    cur[sh_h0[b]*F+f] = hidden[t];
  }
}

__global__ void k_deg(const int* __restrict__ edge, int* __restrict__ deg){
  int e = blockIdx.x*blockDim.x + threadIdx.x;
  if(e<NEDGE) atomicAdd(&deg[edge[NEDGE+e]], 1);
}

__global__ void k_scan(const int* __restrict__ deg, int* __restrict__ csr_start){
  __shared__ int a[2048], b[2048];
  int tid=threadIdx.x;
  for(int i=tid;i<2048;i+=256) a[i] = (i<NNODE)? deg[i] : 0;
  __syncthreads();
  int* src=a; int* dst=b;
  for(int off=1; off<2048; off<<=1){
    for(int i=tid;i<2048;i+=256){
      int v = src[i];
      if(i>=off) v += src[i-off];
      dst[i]=v;
    }
    __syncthreads();
    int* t=src; src=dst; dst=t;
  }
  for(int i=tid;i<=NNODE;i+=256) csr_start[i] = (i==0)?0:src[i-1];
}

// stable CSR fill: one wave per node scans the edge list in order (deterministic order
// within each node's list -> deterministic fp summation across graph replays)
__global__ void k_fill(const int* __restrict__ edge, const int* __restrict__ csr_start,
                       int* __restrict__ csr_src){
  int node = blockIdx.x*4 + (threadIdx.x>>6);
  int lane = threadIdx.x & 63;
  int base = csr_start[node];
  int cnt = 0;
  for(int g=0; g<NEDGE/64; g++){
    int e = g*64 + lane;
    int c = edge[NEDGE+e];
    unsigned long long m = __ballot(c==node);
    if(c==node){
      int pos = base + cnt + __popcll(m & ((1ull<<lane)-1ull));
      csr_src[pos] = edge[e];
    }
    cnt += __popcll(m);
  }
}

// ---------------- per-layer kernels ----------------

// exact top-800-of-8000 with lax.top_k tie semantics (lower index wins ties)
__global__ void k_sel(const float* __restrict__ score, unsigned char* __restrict__ sel){
  __shared__ float s[NN];
  int tid=threadIdx.x;
  float4* s4 = (float4*)s;
  const float4* g4 = (const float4*)score;
  for(int i=tid;i<NN/4;i+=256) s4[i]=g4[i];
  __syncthreads();
  int node = blockIdx.x*32 + (tid>>3);
  int part = tid & 7;
  float si = s[node];
  int rank = 0;
  for(int q=part*(NN/32); q<(part+1)*(NN/32); q++){ // NN/4/8 = 250 float4 per part
    float4 v = s4[q];
    int j = q*4;
    rank += (v.x>si)||(v.x==si && j  <node);
    rank += (v.y>si)||(v.y==si && j+1<node);
    rank += (v.z>si)||(v.z==si && j+2<node);
    rank += (v.w>si)||(v.w==si && j+3<node);
  }
  for(int o=4;o;o>>=1) rank += __shfl_down(rank, o, 8);
  if(part==0) sel[node] = (rank < KTOP) ? 1 : 0;
}

// fp32 GEMM, BM=64 x BN=32, BK=32, 256 thr, thread-tile 2x4.
// MODE 0: AB = cur @ [Wpre_dst|Wpre_src] (+bpre on first 128 cols), out ld 256
// MODE 1: H  = [cur|AGG|AGG*f1|AGG*f2] @ Wpost + bpost   (virtual A)
// MODE 2: cur = cur + (H @ Wlin + blin)                   (residual)
// MODE 3: Z  = (cur@Wl[:128] + Rb[batch] + bl) * cur      (heur*hidden)
// MODE 4: ZZ = relu(Z @ W1 + b1)
#define BM 64
#define BN 32
#define BKK 32
template<int MODE>
__global__ __launch_bounds__(256) void k_gemm(
    const float* __restrict__ A, const float* __restrict__ W,
    const float* __restrict__ bias, float* __restrict__ out,
    const float* __restrict__ AGGp, const float* __restrict__ F1p,
    const float* __restrict__ F2p, const float* __restrict__ RBp,
    const float* __restrict__ CURp, int Ktot)
{
  __shared__ float As[BM][36];
  __shared__ float Bs[BKK][36];
  int tid=threadIdx.x;
  int r0 = blockIdx.x*BM;
  int nblk = blockIdx.y*BN;
  int m0 = (tid>>3)*2;
  int n0 = (tid&7)*4;
  int am = tid>>2, ak=(tid&3)*8;
  int brw = tid>>3, bc=(tid&7)*4;
  float acc[2][4]={};
  for(int k0=0;k0<Ktot;k0+=BKK){
    {
      int row=r0+am;
      const float* src; float mult=1.f;
      if(MODE==1){
        if(k0<F)         src = CURp + row*F   + k0;
        else if(k0<640)  src = AGGp + row*512 + (k0-F);
        else if(k0<1152){ src = AGGp + row*512 + (k0-640);  mult=F1p[row]; }
        else            { src = AGGp + row*512 + (k0-1152); mult=F2p[row]; }
      } else src = A + row*F + k0;
      float4 v0 = *(const float4*)(src+ak);
      float4 v1 = *(const float4*)(src+ak+4);
      if(MODE==1){
        v0.x*=mult; v0.y*=mult; v0.z*=mult; v0.w*=mult;
        v1.x*=mult; v1.y*=mult; v1.z*=mult; v1.w*=mult;
      }
      *(float4*)&As[am][ak]   = v0;
      *(float4*)&As[am][ak+4] = v1;
    }
    {
      int wr=k0+brw, wc=nblk+bc;
      if(MODE==0 && nblk>=F){ wr+=F; wc-=F; } // second weight half for Brow columns
      *(float4*)&Bs[brw][bc] = *(const float4*)&W[wr*F+wc];
    }
    __syncthreads();
    #pragma unroll
    for(int k=0;k<BKK;k++){
      float a0=As[m0][k], a1=As[m0+1][k];
      float4 b=*(float4*)&Bs[k][n0];
      acc[0][0]+=a0*b.x; acc[0][1]+=a0*b.y; acc[0][2]+=a0*b.z; acc[0][3]+=a0*b.w;
      acc[1][0]+=a1*b.x; acc[1][1]+=a1*b.y; acc[1][2]+=a1*b.z; acc[1][3]+=a1*b.w;
    }
    __syncthreads();
  }
  #pragma unroll
  for(int i=0;i<2;i++){
    int rr=r0+m0+i;
    #pragma unroll
    for(int j=0;j<4;j++){
      int cc=nblk+n0+j;
      float v=acc[i][j];
      if(MODE==0){ if(cc<F) v+=bias[cc]; out[rr*256+cc]=v; }
      else if(MODE==1){ out[rr*F+cc]=v+bias[cc]; }
      else if(MODE==2){ out[rr*F+cc]=CURp[rr*F+cc]+(v+bias[cc]); }
      else if(MODE==3){ float h=v+bias[cc]+RBp[(rr/NNODE)*F+cc]; out[rr*F+cc]=h*CURp[rr*F+cc]; }
      else            { float h=v+bias[cc]; out[rr*F+cc]=h>0.f?h:0.f; }
    }
  }
}

// PNA aggregation: one wave per dest node, lane owns 2 features.
// m_e = c + B[src]; accumulate sum, sum^2, max, min over selected sources.
__global__ void k_agg(const float* __restrict__ AB, const unsigned char* __restrict__ sel,
                      const int* __restrict__ csr_start, const int* __restrict__ csr_src,
                      float* __restrict__ AGGo, float* __restrict__ F1o, float* __restrict__ F2o){
  int node = blockIdx.x*4 + (threadIdx.x>>6);
  int lane = threadIdx.x&63;
  int b = node/NNODE;
  int nl = node - b*NNODE;
  int boff = b*NNODE;
  int e0=csr_start[nl], e1=csr_start[nl+1];
  int f0=lane*2;
  float2 c = *(const float2*)&AB[node*256 + f0]; // Acol + bpre
  float s1x=0,s1y=0,s2x=0,s2y=0;
  float mxx=-3e38f,mxy=-3e38f,mnx=3e38f,mny=3e38f;
  int cnt=0;
  for(int base=e0;base<e1;base+=64){
    int nch = e1-base; if(nch>64) nch=64;
    int pack=-1;
    if(lane<nch){
      int sg = csr_src[base+lane]+boff;
      pack = sel[sg] ? sg : -1;
    }
    for(int t=0;t<nch;t++){
      int sg = __shfl(pack, t);
      if(sg>=0){
        float2 v = *(const float2*)&AB[sg*256 + F + f0]; // Brow[src]
        float ma = c.x+v.x, mb = c.y+v.y;
        s1x+=ma; s1y+=mb;
        s2x+=ma*ma; s2y+=mb*mb;
        mxx=fmaxf(mxx,ma); mxy=fmaxf(mxy,mb);
        mnx=fminf(mnx,ma); mny=fminf(mny,mb);
        cnt++;
      }
    }
  }
  float meanx,meany,stdx,stdy,mxox,mxoy,mnox,mnoy;
  if(cnt>0){
    float fc=(float)cnt;
    meanx=s1x/fc; meany=s1y/fc;
    float m2x=s2x/fc, m2y=s2y/fc;
    float vx=m2x-meanx*meanx; if(vx<0.f)vx=0.f;
    float vy=m2y-meany*meany; if(vy<0.f)vy=0.f;
    stdx=sqrtf(vx+EPSSTD); stdy=sqrtf(vy+EPSSTD);
    mxox=mxx; mxoy=mxy; mnox=mnx; mnoy=mny;
  } else {
    meanx=0.f; meany=0.f;
    stdx=sqrtf(EPSSTD); stdy=stdx;
    mxox=0.f; mxoy=0.f; mnox=0.f; mnoy=0.f;
  }
  float logd = logf(fmaxf((float)cnt,1.f)+1.f);
  float2 w0={meanx,meany}; *(float2*)&AGGo[node*512      +f0]=w0;
  float2 w1={mxox,mxoy};   *(float2*)&AGGo[node*512+F    +f0]=w1;
  float2 w2v={mnox,mnoy};  *(float2*)&AGGo[node*512+2*F  +f0]=w2v;
  float2 w3={stdx,stdy};   *(float2*)&AGGo[node*512+3*F  +f0]=w3;
  if(lane==0){ F1o[node]=logd/AVGLOG; F2o[node]=AVGLOG/logd; }
}

__global__ void k_w2(const float* __restrict__ ZZ, const float* __restrict__ W2,
                     const float* __restrict__ b2, float* __restrict__ score){
  int row = blockIdx.x*4 + (threadIdx.x>>6);
  int lane = threadIdx.x&63;
  float2 z = *(const float2*)&ZZ[row*F + lane*2];
  float p = z.x*W2[lane*2] + z.y*W2[lane*2+1];
  for(int o=32;o;o>>=1) p += __shfl_down(p,o);
  if(lane==0) score[row] = p + b2[0];
}

__global__ void k_gather(const float* __restrict__ score, const int* __restrict__ meta_i,
                         float* __restrict__ outp){
  int t = threadIdx.x;
  if(t<128) outp[t] = score[meta_i[16+t]];
}

// ---------------- launch ----------------

extern "C" void kernel_launch(void* const* d_in, const int* in_sizes, int n_in,
                              void* d_out, int out_size, void* d_ws, size_t ws_size,
                              hipStream_t stream){
  const int*   h_index    = (const int*)d_in[0];
  const int*   r_index    = (const int*)d_in[1];
  const int*   t_index    = (const int*)d_in[2];
  const float* hidden     = (const float*)d_in[3];
  const float* rel_hidden = (const float*)d_in[4];
  const int*   edge       = (const int*)d_in[5];
  const float* rel_table  = (const float*)d_in[8];
  const float* Wl =(const float*)d_in[9];   const float* bl =(const float*)d_in[10];
  const float* W1 =(const float*)d_in[11];  const float* b1 =(const float*)d_in[12];
  const float* W2 =(const float*)d_in[13];  const float* b2 =(const float*)d_in[14];
  const float* Wpre =(const float*)d_in[15];  const float* bpre =(const float*)d_in[16];
  const float* Wpost=(const float*)d_in[17];  const float* bpost=(const float*)d_in[18];
  const float* Wlin =(const float*)d_in[19];  const float* blin =(const float*)d_in[20];

  char* ws=(char*)d_ws;
  size_t off=0;
  auto alloc=[&](size_t bytes)->char*{ char* p=ws+off; off=(off+bytes+255)&~(size_t)255; return p; };
  float* cur   =(float*)alloc((size_t)NN*F*4);
  float* AB    =(float*)alloc((size_t)NN*256*4);
  float* AGG   =(float*)alloc((size_t)NN*512*4);
  float* Hb    =(float*)alloc((size_t)NN*F*4);
  float* score =(float*)alloc((size_t)NN*4);
  float* F1b   =(float*)alloc((size_t)NN*4);
  float* F2b   =(float*)alloc((size_t)NN*4);
  float* meta_f=(float*)alloc(2048*4);
  int*   meta_i=(int*)alloc(256*4);
  int*   deg   =(int*)alloc(NNODE*4);
  int*   csr_start=(int*)alloc((NNODE+1)*4);
  int*   csr_src  =(int*)alloc((size_t)NEDGE*4);
  unsigned char* sel=(unsigned char*)alloc(NN);
  float* Zb  = AB;            // AB dead after k_agg -> reuse for score chain
  float* ZZb = AB + (size_t)NN*F;

  k_init<<<512,256,0,stream>>>(cur, deg);
  k_meta<<<1,256,0,stream>>>(h_index,r_index,t_index,hidden,rel_hidden,rel_table,
                             Wl,bl,W1,b1,W2,b2,cur,sel,meta_i,meta_f);
  k_deg <<<250,256,0,stream>>>(edge, deg);
  k_scan<<<1,256,0,stream>>>(deg, csr_start);
  k_fill<<<500,256,0,stream>>>(edge, csr_start, csr_src);

  for(int l=0;l<3;l++){
    if(l) k_sel<<<250,256,0,stream>>>(score, sel);
    k_gemm<0><<<dim3(125,8),256,0,stream>>>(cur, Wpre+(size_t)l*256*F, bpre+l*F, AB,
                                            nullptr,nullptr,nullptr,nullptr,nullptr, F);
    k_agg<<<2000,256,0,stream>>>(AB, sel, csr_start, csr_src, AGG, F1b, F2b);
    k_gemm<1><<<dim3(125,4),256,0,stream>>>(nullptr, Wpost+(size_t)l*1664*F, bpost+l*F, Hb,
                                            AGG, F1b, F2b, nullptr, cur, 1664);
    k_gemm<2><<<dim3(125,4),256,0,stream>>>(Hb, Wlin+(size_t)l*F*F, blin+l*F, cur,
                                            nullptr,nullptr,nullptr,nullptr, cur, F);
    k_gemm<3><<<dim3(125,4),256,0,stream>>>(cur, Wl, bl, Zb,
                                            nullptr,nullptr,nullptr, meta_f+512, cur, F);
    k_gemm<4><<<dim3(125,4),256,0,stream>>>(Zb, W1, b1, ZZb,
                                            nullptr,nullptr,nullptr,nullptr,nullptr, F);
    k_w2<<<2000,256,0,stream>>>(ZZb, W2, b2, score);
  }
  k_gather<<<1,128,0,stream>>>(score, meta_i, (float*)d_out);
}

// Round 2
// 599.319 us; speedup vs baseline: 1.3896x; 1.3896x over previous
//
#include <hip/hip_runtime.h>

#define F 128
#define NNODE 2000
#define NEDGE 64000
#define NBATCH 4
#define NN 8000          // NBATCH*NNODE
#define NRELC 18
#define KTOP 800         // int(0.1*8000)
#define AVGLOG 3.4965075614664802f   // float(np.log(33.0))
#define EPSSTD 1e-5f
#define NCHUNK 250       // NEDGE/256

// ---------------- setup kernels ----------------

__global__ void k_init(float* __restrict__ cur, int* __restrict__ hist){
  int i = blockIdx.x*blockDim.x + threadIdx.x;
  int stride = gridDim.x*blockDim.x;
  for(int t=i;t<NN*F;t+=stride) cur[t]=0.f;
  for(int t=i;t<NCHUNK*NNODE;t+=stride) hist[t]=0;
}

// single block: indices, rel_emb, Rb = rel@Wl[128:], initial scores, sel0, xr scatter
__global__ void k_meta(const int* __restrict__ h_index, const int* __restrict__ r_index,
                       const int* __restrict__ t_index, const float* __restrict__ hidden,
                       const float* __restrict__ rel_hidden, const float* __restrict__ rel_table,
                       const float* __restrict__ Wl, const float* __restrict__ bl,
                       const float* __restrict__ W1, const float* __restrict__ b1,
                       const float* __restrict__ W2, const float* __restrict__ b2,
                       float* __restrict__ cur, unsigned char* __restrict__ sel,
                       int* __restrict__ meta_i, float* __restrict__ meta_f){
  __shared__ int sh_ist[NBATCH], sh_h0[NBATCH], sh_t0[NBATCH], sh_r0[NBATCH];
  __shared__ float sh_rel[NBATCH*F];
  __shared__ float sh_z[F], sh_zz[F];
  __shared__ float sh_sc[NBATCH];
  __shared__ int sh_excl;
  int tid = threadIdx.x;
  if(tid<NBATCH){
    int b=tid;
    int h00=h_index[b*32];
    int ist=1;
    for(int j=1;j<32;j++) if(h_index[b*32+j]!=h00) ist=0;
    sh_ist[b]=ist;
    sh_h0[b] = (ist ? h_index[b*32] : t_index[b*32]) + b*NNODE;
    sh_t0[b] = (ist ? t_index[b*32] : h_index[b*32]) + b*NNODE;
    sh_r0[b] = r_index[b*32] + (ist?0:NRELC);
  }
  __syncthreads();
  if(tid<NBATCH*32){
    int b=tid>>5;
    meta_i[16+tid] = (sh_ist[b] ? t_index[tid] : h_index[tid]) + b*NNODE; // final gather idx
  }
  for(int t=tid;t<NBATCH*F;t+=blockDim.x){
    int b=t>>7, f=t&127;
    float v = rel_table[sh_r0[b]*F+f];
    sh_rel[t]=v; meta_f[t]=v;
  }
  __syncthreads();
  // Rb[b][f] = sum_k rel[b][k]*Wl[128+k][f]
  for(int t=tid;t<NBATCH*F;t+=blockDim.x){
    int b=t>>7, f=t&127;
    float acc=0.f;
    for(int k=0;k<F;k++) acc += sh_rel[b*F+k]*Wl[(F+k)*F+f];
    meta_f[512+t]=acc;
  }
  __syncthreads();
  // initial scores sc[b] = _score(hidden_b, rel_b)
  for(int b=0;b<NBATCH;b++){
    if(tid<F){
      float acc=0.f;
      for(int k=0;k<F;k++) acc += hidden[b*F+k]*Wl[k*F+tid];
      float heur = acc + meta_f[512+b*F+tid] + bl[tid];
      sh_z[tid] = heur*hidden[b*F+tid];
    }
    __syncthreads();
    if(tid<F){
      float acc=0.f;
      for(int k=0;k<F;k++) acc += sh_z[k]*W1[k*F+tid];
      acc += b1[tid];
      sh_zz[tid] = acc>0.f?acc:0.f;
    }
    __syncthreads();
    if(tid==0){
      float s=0.f;
      for(int k=0;k<F;k++) s += sh_zz[k]*W2[k];
      sh_sc[b] = s + b2[0];
      meta_f[1024+b]=sh_sc[b];
    }
    __syncthreads();
  }
  if(tid==0){
    // layer-0 top_k over repeat(s0,N): only first-8000 entries matter; all zero-ties
    // get selected (k-Z >= 1.59M >> 8000). Exclusion only if batch0's h0 node < 4
    // (so its repeated segment lands below 8000) AND its score is negative.
    sh_excl = (sh_h0[0]<4 && sh_sc[0]<0.f) ? sh_h0[0] : -1;
    meta_i[8]=sh_excl;
  }
  __syncthreads();
  int ex = sh_excl;
  for(int t=tid;t<NN;t+=blockDim.x)
    sel[t] = (ex>=0 && (t/NNODE)==ex) ? 0 : 1;
  // xr scatter: t rows first, then h rows (h wins collisions, matching .at[].set order)
  for(int t=tid;t<NBATCH*F;t+=blockDim.x){
    int b=t>>7, f=t&127;
    cur[sh_t0[b]*F+f] = rel_hidden[t];
  }
  __syncthreads();
  for(int t=tid;t<NBATCH*F;t+=blockDim.x){
    int b=t>>7, f=t&127;
    cur[sh_h0[b]*F+f] = hidden[t];
  }
}

// stable counting-sort CSR build, O(E):
// k_hist: per-256-edge chunk, stable in-chunk rank + per-(chunk,node) count
__global__ __launch_bounds__(256) void k_hist(const int* __restrict__ edge,
                                              int* __restrict__ hist, int* __restrict__ rank){
  __shared__ int dsts[256];
  int chunk = blockIdx.x;
  int tid = threadIdx.x;
  int e = chunk*256 + tid;
  int d = edge[NEDGE + e];
  dsts[tid] = d;
  __syncthreads();
  int before=0, after=0;
  #pragma unroll 8
  for(int t=0;t<256;t++){
    int dt = dsts[t];                   // broadcast LDS read
    before += (dt==d) & (t<tid);
    after  += (dt==d) & (t>tid);
  }
  rank[e] = before;
  if(after==0) hist[chunk*NNODE + d] = before+1;   // last occurrence writes chunk count
}

// per-node exclusive prefix across chunks (coalesced); also emits deg
__global__ void k_chunkscan(int* __restrict__ hist, int* __restrict__ deg){
  int node = blockIdx.x*blockDim.x + threadIdx.x;
  if(node>=NNODE) return;
  int run=0;
  for(int c=0;c<NCHUNK;c++){
    int v = hist[c*NNODE+node];
    hist[c*NNODE+node] = run;
    run += v;
  }
  deg[node]=run;
}

__global__ void k_scan(const int* __restrict__ deg, int* __restrict__ csr_start){
  __shared__ int a[2048], b[2048];
  int tid=threadIdx.x;
  for(int i=tid;i<2048;i+=256) a[i] = (i<NNODE)? deg[i] : 0;
  __syncthreads();
  int* src=a; int* dst=b;
  for(int off=1; off<2048; off<<=1){
    for(int i=tid;i<2048;i+=256){
      int v = src[i];
      if(i>=off) v += src[i-off];
      dst[i]=v;
    }
    __syncthreads();
    int* t=src; src=dst; dst=t;
  }
  for(int i=tid;i<=NNODE;i+=256) csr_start[i] = (i==0)?0:src[i-1];
}

// final stable scatter: pos = csr_start + chunk prefix + in-chunk rank
__global__ void k_scatter(const int* __restrict__ edge, const int* __restrict__ hist,
                          const int* __restrict__ rank, const int* __restrict__ csr_start,
                          int* __restrict__ csr_src){
  int e = blockIdx.x*blockDim.x + threadIdx.x;
  if(e<NEDGE){
    int d = edge[NEDGE+e];
    int pos = csr_start[d] + hist[(e>>8)*NNODE + d] + rank[e];
    csr_src[pos] = edge[e];
  }
}

// ---------------- per-layer kernels ----------------

// exact top-800-of-8000 with lax.top_k tie semantics (lower index wins ties)
__global__ void k_sel(const float* __restrict__ score, unsigned char* __restrict__ sel){
  __shared__ float s[NN];
  int tid=threadIdx.x;
  float4* s4 = (float4*)s;
  const float4* g4 = (const float4*)score;
  for(int i=tid;i<NN/4;i+=256) s4[i]=g4[i];
  __syncthreads();
  int node = blockIdx.x*32 + (tid>>3);
  int part = tid & 7;
  float si = s[node];
  int rank = 0;
  for(int q=part*(NN/32); q<(part+1)*(NN/32); q++){
    float4 v = s4[q];
    int j = q*4;
    rank += (v.x>si)||(v.x==si && j  <node);
    rank += (v.y>si)||(v.y==si && j+1<node);
    rank += (v.z>si)||(v.z==si && j+2<node);
    rank += (v.w>si)||(v.w==si && j+3<node);
  }
  for(int o=4;o;o>>=1) rank += __shfl_down(rank, o, 8);
  if(part==0) sel[node] = (rank < KTOP) ? 1 : 0;
}

// fp32 GEMM, BM=64 x BN=32, BK=32, 256 thr, thread-tile 2x4.
// MODE 0: AB = cur @ [Wpre_dst|Wpre_src] (+bpre on first 128 cols), out ld 256
// MODE 1: H  = [cur|AGG|AGG*f1|AGG*f2] @ Wpost + bpost   (virtual A)
// MODE 2: cur = cur + (H @ Wlin + blin)                   (residual)
// MODE 3: Z  = (cur@Wl[:128] + Rb[batch] + bl) * cur      (heur*hidden)
// MODE 4: ZZ = relu(Z @ W1 + b1)
#define BM 64
#define BN 32
#define BKK 32
template<int MODE>
__global__ __launch_bounds__(256) void k_gemm(
    const float* __restrict__ A, const float* __restrict__ W,
    const float* __restrict__ bias, float* __restrict__ out,
    const float* __restrict__ AGGp, const float* __restrict__ F1p,
    const float* __restrict__ F2p, const float* __restrict__ RBp,
    const float* __restrict__ CURp, int Ktot)
{
  __shared__ float As[BM][36];
  __shared__ float Bs[BKK][36];
  int tid=threadIdx.x;
  int r0 = blockIdx.x*BM;
  int nblk = blockIdx.y*BN;
  int m0 = (tid>>3)*2;
  int n0 = (tid&7)*4;
  int am = tid>>2, ak=(tid&3)*8;
  int brw = tid>>3, bc=(tid&7)*4;
  float acc[2][4]={};
  for(int k0=0;k0<Ktot;k0+=BKK){
    {
      int row=r0+am;
      const float* src; float mult=1.f;
      if(MODE==1){
        if(k0<F)         src = CURp + row*F   + k0;
        else if(k0<640)  src = AGGp + row*512 + (k0-F);
        else if(k0<1152){ src = AGGp + row*512 + (k0-640);  mult=F1p[row]; }
        else            { src = AGGp + row*512 + (k0-1152); mult=F2p[row]; }
      } else src = A + row*F + k0;
      float4 v0 = *(const float4*)(src+ak);
      float4 v1 = *(const float4*)(src+ak+4);
      if(MODE==1){
        v0.x*=mult; v0.y*=mult; v0.z*=mult; v0.w*=mult;
        v1.x*=mult; v1.y*=mult; v1.z*=mult; v1.w*=mult;
      }
      *(float4*)&As[am][ak]   = v0;
      *(float4*)&As[am][ak+4] = v1;
    }
    {
      int wr=k0+brw, wc=nblk+bc;
      if(MODE==0 && nblk>=F){ wr+=F; wc-=F; } // second weight half for Brow columns
      *(float4*)&Bs[brw][bc] = *(const float4*)&W[wr*F+wc];
    }
    __syncthreads();
    #pragma unroll
    for(int k=0;k<BKK;k++){
      float a0=As[m0][k], a1=As[m0+1][k];
      float4 b=*(float4*)&Bs[k][n0];
      acc[0][0]+=a0*b.x; acc[0][1]+=a0*b.y; acc[0][2]+=a0*b.z; acc[0][3]+=a0*b.w;
      acc[1][0]+=a1*b.x; acc[1][1]+=a1*b.y; acc[1][2]+=a1*b.z; acc[1][3]+=a1*b.w;
    }
    __syncthreads();
  }
  #pragma unroll
  for(int i=0;i<2;i++){
    int rr=r0+m0+i;
    #pragma unroll
    for(int j=0;j<4;j++){
      int cc=nblk+n0+j;
      float v=acc[i][j];
      if(MODE==0){ if(cc<F) v+=bias[cc]; out[rr*256+cc]=v; }
      else if(MODE==1){ out[rr*F+cc]=v+bias[cc]; }
      else if(MODE==2){ out[rr*F+cc]=CURp[rr*F+cc]+(v+bias[cc]); }
      else if(MODE==3){ float h=v+bias[cc]+RBp[(rr/NNODE)*F+cc]; out[rr*F+cc]=h*CURp[rr*F+cc]; }
      else            { float h=v+bias[cc]; out[rr*F+cc]=h>0.f?h:0.f; }
    }
  }
}

// PNA aggregation: one wave per dest node, lane owns 2 features.
__global__ void k_agg(const float* __restrict__ AB, const unsigned char* __restrict__ sel,
                      const int* __restrict__ csr_start, const int* __restrict__ csr_src,
                      float* __restrict__ AGGo, float* __restrict__ F1o, float* __restrict__ F2o){
  int node = blockIdx.x*4 + (threadIdx.x>>6);
  int lane = threadIdx.x&63;
  int b = node/NNODE;
  int nl = node - b*NNODE;
  int boff = b*NNODE;
  int e0=csr_start[nl], e1=csr_start[nl+1];
  int f0=lane*2;
  float2 c = *(const float2*)&AB[node*256 + f0]; // Acol + bpre
  float s1x=0,s1y=0,s2x=0,s2y=0;
  float mxx=-3e38f,mxy=-3e38f,mnx=3e38f,mny=3e38f;
  int cnt=0;
  for(int base=e0;base<e1;base+=64){
    int nch = e1-base; if(nch>64) nch=64;
    int pack=-1;
    if(lane<nch){
      int sg = csr_src[base+lane]+boff;
      pack = sel[sg] ? sg : -1;
    }
    for(int t=0;t<nch;t++){
      int sg = __shfl(pack, t);
      if(sg>=0){
        float2 v = *(const float2*)&AB[sg*256 + F + f0]; // Brow[src]
        float ma = c.x+v.x, mb = c.y+v.y;
        s1x+=ma; s1y+=mb;
        s2x+=ma*ma; s2y+=mb*mb;
        mxx=fmaxf(mxx,ma); mxy=fmaxf(mxy,mb);
        mnx=fminf(mnx,ma); mny=fminf(mny,mb);
        cnt++;
      }
    }
  }
  float meanx,meany,stdx,stdy,mxox,mxoy,mnox,mnoy;
  if(cnt>0){
    float fc=(float)cnt;
    meanx=s1x/fc; meany=s1y/fc;
    float m2x=s2x/fc, m2y=s2y/fc;
    float vx=m2x-meanx*meanx; if(vx<0.f)vx=0.f;
    float vy=m2y-meany*meany; if(vy<0.f)vy=0.f;
    stdx=sqrtf(vx+EPSSTD); stdy=sqrtf(vy+EPSSTD);
    mxox=mxx; mxoy=mxy; mnox=mnx; mnoy=mny;
  } else {
    meanx=0.f; meany=0.f;
    stdx=sqrtf(EPSSTD); stdy=stdx;
    mxox=0.f; mxoy=0.f; mnox=0.f; mnoy=0.f;
  }
  float logd = logf(fmaxf((float)cnt,1.f)+1.f);
  float2 w0={meanx,meany}; *(float2*)&AGGo[node*512      +f0]=w0;
  float2 w1={mxox,mxoy};   *(float2*)&AGGo[node*512+F    +f0]=w1;
  float2 w2v={mnox,mnoy};  *(float2*)&AGGo[node*512+2*F  +f0]=w2v;
  float2 w3={stdx,stdy};   *(float2*)&AGGo[node*512+3*F  +f0]=w3;
  if(lane==0){ F1o[node]=logd/AVGLOG; F2o[node]=AVGLOG/logd; }
}

__global__ void k_w2(const float* __restrict__ ZZ, const float* __restrict__ W2,
                     const float* __restrict__ b2, float* __restrict__ score){
  int row = blockIdx.x*4 + (threadIdx.x>>6);
  int lane = threadIdx.x&63;
  float2 z = *(const float2*)&ZZ[row*F + lane*2];
  float p = z.x*W2[lane*2] + z.y*W2[lane*2+1];
  for(int o=32;o;o>>=1) p += __shfl_down(p,o);
  if(lane==0) score[row] = p + b2[0];
}

__global__ void k_gather(const float* __restrict__ score, const int* __restrict__ meta_i,
                         float* __restrict__ outp){
  int t = threadIdx.x;
  if(t<128) outp[t] = score[meta_i[16+t]];
}

// ---------------- launch ----------------

extern "C" void kernel_launch(void* const* d_in, const int* in_sizes, int n_in,
                              void* d_out, int out_size, void* d_ws, size_t ws_size,
                              hipStream_t stream){
  const int*   h_index    = (const int*)d_in[0];
  const int*   r_index    = (const int*)d_in[1];
  const int*   t_index    = (const int*)d_in[2];
  const float* hidden     = (const float*)d_in[3];
  const float* rel_hidden = (const float*)d_in[4];
  const int*   edge       = (const int*)d_in[5];
  const float* rel_table  = (const float*)d_in[8];
  const float* Wl =(const float*)d_in[9];   const float* bl =(const float*)d_in[10];
  const float* W1 =(const float*)d_in[11];  const float* b1 =(const float*)d_in[12];
  const float* W2 =(const float*)d_in[13];  const float* b2 =(const float*)d_in[14];
  const float* Wpre =(const float*)d_in[15];  const float* bpre =(const float*)d_in[16];
  const float* Wpost=(const float*)d_in[17];  const float* bpost=(const float*)d_in[18];
  const float* Wlin =(const float*)d_in[19];  const float* blin =(const float*)d_in[20];

  char* ws=(char*)d_ws;
  size_t off=0;
  auto alloc=[&](size_t bytes)->char*{ char* p=ws+off; off=(off+bytes+255)&~(size_t)255; return p; };
  float* cur   =(float*)alloc((size_t)NN*F*4);
  float* AB    =(float*)alloc((size_t)NN*256*4);
  float* AGG   =(float*)alloc((size_t)NN*512*4);
  float* Hb    =(float*)alloc((size_t)NN*F*4);
  float* score =(float*)alloc((size_t)NN*4);
  float* F1b   =(float*)alloc((size_t)NN*4);
  float* F2b   =(float*)alloc((size_t)NN*4);
  float* meta_f=(float*)alloc(2048*4);
  int*   meta_i=(int*)alloc(256*4);
  int*   deg   =(int*)alloc(NNODE*4);
  int*   csr_start=(int*)alloc((NNODE+1)*4);
  int*   csr_src  =(int*)alloc((size_t)NEDGE*4);
  int*   hist  =(int*)alloc((size_t)NCHUNK*NNODE*4);
  int*   rank  =(int*)alloc((size_t)NEDGE*4);
  unsigned char* sel=(unsigned char*)alloc(NN);
  float* Zb  = AB;            // AB dead after k_agg -> reuse for score chain
  float* ZZb = AB + (size_t)NN*F;

  k_init<<<512,256,0,stream>>>(cur, hist);
  k_meta<<<1,256,0,stream>>>(h_index,r_index,t_index,hidden,rel_hidden,rel_table,
                             Wl,bl,W1,b1,W2,b2,cur,sel,meta_i,meta_f);
  k_hist<<<NCHUNK,256,0,stream>>>(edge, hist, rank);
  k_chunkscan<<<8,256,0,stream>>>(hist, deg);
  k_scan<<<1,256,0,stream>>>(deg, csr_start);
  k_scatter<<<250,256,0,stream>>>(edge, hist, rank, csr_start, csr_src);

  for(int l=0;l<3;l++){
    if(l) k_sel<<<250,256,0,stream>>>(score, sel);
    k_gemm<0><<<dim3(125,8),256,0,stream>>>(cur, Wpre+(size_t)l*256*F, bpre+l*F, AB,
                                            nullptr,nullptr,nullptr,nullptr,nullptr, F);
    k_agg<<<2000,256,0,stream>>>(AB, sel, csr_start, csr_src, AGG, F1b, F2b);
    k_gemm<1><<<dim3(125,4),256,0,stream>>>(nullptr, Wpost+(size_t)l*1664*F, bpost+l*F, Hb,
                                            AGG, F1b, F2b, nullptr, cur, 1664);
    k_gemm<2><<<dim3(125,4),256,0,stream>>>(Hb, Wlin+(size_t)l*F*F, blin+l*F, cur,
                                            nullptr,nullptr,nullptr,nullptr, cur, F);
    k_gemm<3><<<dim3(125,4),256,0,stream>>>(cur, Wl, bl, Zb,
                                            nullptr,nullptr,nullptr, meta_f+512, cur, F);
    k_gemm<4><<<dim3(125,4),256,0,stream>>>(Zb, W1, b1, ZZb,
                                            nullptr,nullptr,nullptr,nullptr,nullptr, F);
    k_w2<<<2000,256,0,stream>>>(ZZb, W2, b2, score);
  }
  k_gather<<<1,128,0,stream>>>(score, meta_i, (float*)d_out);
}